// Round 4
// baseline (320.686 us; speedup 1.0000x reference)
//
#include <hip/hip_runtime.h>
#include <hip/hip_bf16.h>

#define NDIM 4096
#define DDIM 256
#define KORD 8

#define BM 128
#define BN 128
#define BK 32
#define SPLITK 8
#define KSLICE (NDIM / SPLITK)    // 512
#define NSTEP (KSLICE / BK)       // 16
#define ELEMS (NDIM * DDIM)       // 1048576

// per-buffer LDS layout (ushort offsets): AsHi 0 | AsLo 4096 | BsHi 8192 | BsLo 12288
#define LBUF 16384                // ushorts per buffer (32 KB)

typedef __attribute__((ext_vector_type(8))) short bf16x8;
typedef __attribute__((ext_vector_type(4))) float f32x4;

__device__ __forceinline__ ushort f2bf(float v) {
    __hip_bfloat16 h = __float2bfloat16(v);
    return *reinterpret_cast<ushort*>(&h);
}
__device__ __forceinline__ float bf2f(ushort u) {
    __hip_bfloat16 h = *reinterpret_cast<__hip_bfloat16*>(&u);
    return __bfloat162float(h);
}
__device__ __forceinline__ void split2(float v, ushort& h, ushort& l) {
    h = f2bf(v);
    l = f2bf(v - bf2f(h));
}
__device__ __forceinline__ uint4 pack8(const ushort* s) {
    uint4 r;
    r.x = (uint)s[0] | ((uint)s[1] << 16);
    r.y = (uint)s[2] | ((uint)s[3] << 16);
    r.z = (uint)s[4] | ((uint)s[5] << 16);
    r.w = (uint)s[6] | ((uint)s[7] << 16);
    return r;
}

// ---------------- split L into bf16 hi/lo (once per call) ----------------
__global__ __launch_bounds__(256)
void split_L(const float* __restrict__ L, ushort* __restrict__ Lhi,
             ushort* __restrict__ Llo)
{
    const int e0 = (blockIdx.x * 256 + threadIdx.x) * 8;
    float4 a = *(const float4*)&L[e0];
    float4 b = *(const float4*)&L[e0 + 4];
    float v[8] = {a.x, a.y, a.z, a.w, b.x, b.y, b.z, b.w};
    ushort h[8], l[8];
#pragma unroll
    for (int j = 0; j < 8; ++j) split2(v[j], h[j], l[j]);
    *(uint4*)&Lhi[e0] = pack8(h);
    *(uint4*)&Llo[e0] = pack8(l);
}

// ---------------- z7 = c7*x -> transposed bf16 splits ----------------
__global__ __launch_bounds__(256)
void split_x(const float* __restrict__ x, const float* __restrict__ coeffs,
             ushort* __restrict__ yhiT, ushort* __restrict__ yloT)
{
    __shared__ float tile[64][65];
    const float c = coeffs[KORD - 1];
    const int m0 = blockIdx.x * 64, n0 = blockIdx.y * 64;
    const int t = threadIdx.x;
    const int ml = t >> 2, n4 = (t & 3) * 16;
#pragma unroll
    for (int j = 0; j < 4; ++j) {
        float4 v = *(const float4*)&x[(size_t)(m0 + ml) * DDIM + n0 + n4 + j * 4];
        tile[ml][n4 + j * 4 + 0] = c * v.x;
        tile[ml][n4 + j * 4 + 1] = c * v.y;
        tile[ml][n4 + j * 4 + 2] = c * v.z;
        tile[ml][n4 + j * 4 + 3] = c * v.w;
    }
    __syncthreads();
    const int nl = t >> 2, m16 = (t & 3) * 16;
    ushort h[16], l[16];
#pragma unroll
    for (int j = 0; j < 16; ++j) split2(tile[m16 + j][nl], h[j], l[j]);
    const size_t ob = (size_t)(n0 + nl) * NDIM + m0 + m16;
    *(uint4*)&yhiT[ob]     = pack8(h);
    *(uint4*)&yhiT[ob + 8] = pack8(h + 8);
    *(uint4*)&yloT[ob]     = pack8(l);
    *(uint4*)&yloT[ob + 8] = pack8(l + 8);
}

// ---------------- fused 3-product MFMA partial GEMM, counted-vmcnt pipeline ----
__global__ __launch_bounds__(256, 2)
void gemm_fused(const ushort* __restrict__ Lhi, const ushort* __restrict__ Llo,
                const ushort* __restrict__ yhiT, const ushort* __restrict__ yloT,
                float* __restrict__ P)
{
    __shared__ ushort lds[2 * LBUF];   // 64 KB

    // z = XCD id (bid%8): each XCD owns one K-slice -> its B slice is L2-resident,
    // A-panel nt-pairs are temporally adjacent on the same XCD.
    const int bid  = blockIdx.x;
    const int z    = bid & 7;               // K slice 0..7
    const int slot = bid >> 3;              // 0..63
    const int nt   = slot & 1;
    const int mt   = slot >> 1;             // 0..31

    const int m0 = mt * BM, n0 = nt * BN;
    const int kb = z * KSLICE;

    const int t = threadIdx.x;
    const int lane = t & 63, wid = t >> 6;
    const int wr = wid >> 1, wc = wid & 1;  // 2x2 wave grid, wave tile 64x64

    // ---- staging: 8 x global_load_lds(16B) per thread per tile
    const int rowS = t >> 2;                        // 0..63
    const int ksw  = ((t & 3) ^ (rowS & 3)) * 8;    // XOR k-slot swizzle (involution)
    const ushort* sAh = Lhi  + (size_t)(m0 + rowS) * NDIM + kb + ksw;
    const ushort* sAl = Llo  + (size_t)(m0 + rowS) * NDIM + kb + ksw;
    const ushort* sBh = yhiT + (size_t)(n0 + rowS) * NDIM + kb + ksw;
    const ushort* sBl = yloT + (size_t)(n0 + rowS) * NDIM + kb + ksw;
    const size_t R64 = (size_t)64 * NDIM;
    const int wb = wid * 512;               // wave-uniform chunk base (ushorts)

#define GLD(src, dstoff)                                                     \
    __builtin_amdgcn_global_load_lds(                                        \
        (const __attribute__((address_space(1))) uint*)(src),                \
        (__attribute__((address_space(3))) uint*)(&lds[dstoff]), 16, 0, 0)

#define STAGE(buf, ko)                                                       \
    do {                                                                     \
        const int _b = (buf) * LBUF;                                         \
        GLD(sAh + (ko),        _b + wb);                                     \
        GLD(sAh + (ko) + R64,  _b + 2048 + wb);                              \
        GLD(sAl + (ko),        _b + 4096 + wb);                              \
        GLD(sAl + (ko) + R64,  _b + 6144 + wb);                              \
        GLD(sBh + (ko),        _b + 8192 + wb);                              \
        GLD(sBh + (ko) + R64,  _b + 10240 + wb);                             \
        GLD(sBl + (ko),        _b + 12288 + wb);                             \
        GLD(sBl + (ko) + R64,  _b + 14336 + wb);                             \
    } while (0)

    // ---- fragment read offsets (same involution as the source swizzle)
    const int frow = lane & 15;
    const int fsw  = (((lane >> 4) ^ (frow & 3))) * 8;
    const int arB  = (wr * 64 + frow) * 32 + fsw;   // A row-base (ushorts)
    const int brB  = (wc * 64 + frow) * 32 + fsw;   // B row-base (ushorts)

    f32x4 acc[4][4];
#pragma unroll
    for (int i = 0; i < 4; ++i)
#pragma unroll
        for (int j = 0; j < 4; ++j) acc[i][j] = (f32x4){0.f, 0.f, 0.f, 0.f};

    // prologue: stage tiles 0,1
    STAGE(0, 0);
    STAGE(1, BK);

    for (int step = 0; step < NSTEP; ++step) {
        // (1) tile[step] ready: counted wait (tile[step+1]'s 8 loads stay in flight)
        if (step + 1 < NSTEP)
            asm volatile("s_waitcnt vmcnt(8)" ::: "memory");
        else
            asm volatile("s_waitcnt vmcnt(0)" ::: "memory");
        __builtin_amdgcn_sched_barrier(0);
        __builtin_amdgcn_s_barrier();
        __builtin_amdgcn_sched_barrier(0);

        // (2) read fragments
        const int b = (step & 1) * LBUF;
        bf16x8 ah[4], al[4], bh[4], bl[4];
#pragma unroll
        for (int i = 0; i < 4; ++i) {
            ah[i] = *(const bf16x8*)&lds[b + arB + i * 512];
            al[i] = *(const bf16x8*)&lds[b + arB + i * 512 + 4096];
        }
#pragma unroll
        for (int j = 0; j < 4; ++j) {
            bh[j] = *(const bf16x8*)&lds[b + brB + j * 512 + 8192];
            bl[j] = *(const bf16x8*)&lds[b + brB + j * 512 + 12288];
        }
        asm volatile("s_waitcnt lgkmcnt(0)" ::: "memory");
        __builtin_amdgcn_sched_barrier(0);
        __builtin_amdgcn_s_barrier();      // all waves done reading this buffer
        __builtin_amdgcn_sched_barrier(0);

        // (3) prefetch tile[step+2] into the buffer just read
        if (step + 2 < NSTEP) STAGE(step & 1, (step + 2) * BK);

        // (4) MFMA cluster
        __builtin_amdgcn_s_setprio(1);
#pragma unroll
        for (int i = 0; i < 4; ++i)
#pragma unroll
            for (int j = 0; j < 4; ++j) {
                acc[i][j] = __builtin_amdgcn_mfma_f32_16x16x32_bf16(
                    ah[i], bh[j], acc[i][j], 0, 0, 0);
                acc[i][j] = __builtin_amdgcn_mfma_f32_16x16x32_bf16(
                    ah[i], bl[j], acc[i][j], 0, 0, 0);
                acc[i][j] = __builtin_amdgcn_mfma_f32_16x16x32_bf16(
                    al[i], bh[j], acc[i][j], 0, 0, 0);
            }
        __builtin_amdgcn_s_setprio(0);
    }
#undef STAGE
#undef GLD

    float* Pp = P + (size_t)z * ELEMS;
    const int crow = (lane >> 4) * 4;
    const int ccol = lane & 15;
#pragma unroll
    for (int i = 0; i < 4; ++i)
#pragma unroll
        for (int j = 0; j < 4; ++j)
#pragma unroll
            for (int r = 0; r < 4; ++r)
                Pp[(size_t)(m0 + wr * 64 + i * 16 + crow + r) * DDIM
                   + n0 + wc * 64 + j * 16 + ccol] = acc[i][j][r];
}

// ---------------- z = sum(P) + c*x ; re-split transposed (or final out) ----------------
__global__ __launch_bounds__(256)
void combine(const float* __restrict__ P, const float* __restrict__ x,
             const float* __restrict__ coeffs, const int ci, const int last,
             ushort* __restrict__ yhiT, ushort* __restrict__ yloT,
             float* __restrict__ out)
{
    __shared__ float tile[64][65];
    const float c = coeffs[ci];
    const int m0 = blockIdx.x * 64, n0 = blockIdx.y * 64;
    const int t = threadIdx.x;
    const int ml = t >> 2, n4 = (t & 3) * 16;
    const size_t base = (size_t)(m0 + ml) * DDIM + n0 + n4;
    float acc[16];
#pragma unroll
    for (int j = 0; j < 4; ++j) {
        float4 v = *(const float4*)&x[base + j * 4];
        acc[j * 4 + 0] = c * v.x; acc[j * 4 + 1] = c * v.y;
        acc[j * 4 + 2] = c * v.z; acc[j * 4 + 3] = c * v.w;
    }
#pragma unroll
    for (int s = 0; s < SPLITK; ++s) {
        const float* Pp = P + (size_t)s * ELEMS;
#pragma unroll
        for (int j = 0; j < 4; ++j) {
            float4 v = *(const float4*)&Pp[base + j * 4];
            acc[j * 4 + 0] += v.x; acc[j * 4 + 1] += v.y;
            acc[j * 4 + 2] += v.z; acc[j * 4 + 3] += v.w;
        }
    }
    if (last) {
#pragma unroll
        for (int j = 0; j < 4; ++j) {
            float4 v;
            v.x = acc[j * 4 + 0]; v.y = acc[j * 4 + 1];
            v.z = acc[j * 4 + 2]; v.w = acc[j * 4 + 3];
            *(float4*)&out[base + j * 4] = v;
        }
        return;
    }
#pragma unroll
    for (int j = 0; j < 16; ++j) tile[ml][n4 + j] = acc[j];
    __syncthreads();
    const int nl = t >> 2, m16 = (t & 3) * 16;
    ushort h[16], l[16];
#pragma unroll
    for (int j = 0; j < 16; ++j) split2(tile[m16 + j][nl], h[j], l[j]);
    const size_t ob = (size_t)(n0 + nl) * NDIM + m0 + m16;
    *(uint4*)&yhiT[ob]     = pack8(h);
    *(uint4*)&yhiT[ob + 8] = pack8(h + 8);
    *(uint4*)&yloT[ob]     = pack8(l);
    *(uint4*)&yloT[ob + 8] = pack8(l + 8);
}

extern "C" void kernel_launch(void* const* d_in, const int* in_sizes, int n_in,
                              void* d_out, int out_size, void* d_ws, size_t ws_size,
                              hipStream_t stream)
{
    const float* L      = (const float*)d_in[0];
    const float* x      = (const float*)d_in[1];
    const float* coeffs = (const float*)d_in[2];
    float* out = (float*)d_out;

    // Workspace (~100 MB): Lhi 32MB | Llo 32MB | P 32MB | yhiT 2MB | yloT 2MB
    char* w = (char*)d_ws;
    ushort* Lhi  = (ushort*)w;
    ushort* Llo  = (ushort*)(w + (size_t)NDIM * NDIM * 2);
    float*  Pp   = (float*)(w + (size_t)NDIM * NDIM * 4);
    ushort* yhiT = (ushort*)(w + (size_t)NDIM * NDIM * 4 + (size_t)SPLITK * ELEMS * 4);
    ushort* yloT = yhiT + (size_t)DDIM * NDIM;

    split_L<<<NDIM * NDIM / (256 * 8), 256, 0, stream>>>(L, Lhi, Llo);
    split_x<<<dim3(NDIM / 64, DDIM / 64), 256, 0, stream>>>(x, coeffs, yhiT, yloT);

    for (int i = KORD - 2; i >= 0; --i) {   // Horner: z <- L z + c_i x
        gemm_fused<<<SPLITK * 64, 256, 0, stream>>>(Lhi, Llo, yhiT, yloT, Pp);
        combine<<<dim3(NDIM / 64, DDIM / 64), 256, 0, stream>>>(
            Pp, x, coeffs, i, (i == 0) ? 1 : 0, yhiT, yloT, out);
    }
}